// Round 19
// baseline (390.968 us; speedup 1.0000x reference)
//
#include <hip/hip_runtime.h>
#include <hip/hip_bf16.h>

typedef __hip_bfloat16 bf16;
typedef __bf16 bf16x8 __attribute__((ext_vector_type(8)));
typedef float f32x4 __attribute__((ext_vector_type(4)));
typedef short short8 __attribute__((ext_vector_type(8)));
typedef short short4v __attribute__((ext_vector_type(4)));

#define NH 24
#define NKV 8
#define HD 128
#define SEQ 2048
#define NREP 3
#define QKVD 5120              // fused QKV row stride (3072 + 1024 + 1024)
#define KOFF 3072              // K region offset in fused row
#define VOFF 4096              // V region offset in fused row
#define SCALE_LOG2 0.12751745f  // (1/sqrt(128)) * log2(e) — folded into Q at projection

__device__ inline void gload16(const void* g, void* l) {
  __builtin_amdgcn_global_load_lds(
      (const __attribute__((address_space(1))) void*)g,
      (__attribute__((address_space(3))) void*)l, 16, 0, 0);
}

__device__ inline short bfbits(float v) {
  return __builtin_bit_cast(short, __float2bfloat16(v));
}

// ---------------- cast f32 -> bf16 (vectorized) ----------------
__global__ void cast_f32_bf16(const float* __restrict__ in, bf16* __restrict__ out, int n4) {
  int i = blockIdx.x * 256 + threadIdx.x;
  if (i >= n4) return;
  float4 v = reinterpret_cast<const float4*>(in)[i];
  ushort4 u;
  u.x = __builtin_bit_cast(unsigned short, __float2bfloat16(v.x));
  u.y = __builtin_bit_cast(unsigned short, __float2bfloat16(v.y));
  u.z = __builtin_bit_cast(unsigned short, __float2bfloat16(v.z));
  u.w = __builtin_bit_cast(unsigned short, __float2bfloat16(v.w));
  reinterpret_cast<ushort4*>(out)[i] = u;
}

// ---------------- merged transpose + cast of all 4 weights (K = 3072 for all) --------
// z: 0 = wq -> wqkvT[0..3072), 1 = wk -> wqkvT[KOFF..), 2 = wv -> wqkvT[VOFF..),
//    3 = wo -> woT. Blocks with n0 >= N exit early (z = 1,2 use only 1/3 of grid-x).
__global__ void transpose_cast_all(const float* __restrict__ wq, const float* __restrict__ wk,
                                   const float* __restrict__ wv, const float* __restrict__ wo,
                                   bf16* __restrict__ wqkvT, bf16* __restrict__ woT) {
  __shared__ bf16 tile[32][33];
  const int K = 3072;
  int z = blockIdx.z;
  const float* W;
  bf16* WT;
  int N;
  if (z == 0)      { W = wq; WT = wqkvT;                       N = 3072; }
  else if (z == 1) { W = wk; WT = wqkvT + (size_t)KOFF * K;    N = 1024; }
  else if (z == 2) { W = wv; WT = wqkvT + (size_t)VOFF * K;    N = 1024; }
  else             { W = wo; WT = woT;                         N = 3072; }
  int n0 = blockIdx.x * 32, k0 = blockIdx.y * 32;
  if (n0 >= N) return;
  int tx = threadIdx.x, ty = threadIdx.y;  // (32, 8)
#pragma unroll
  for (int i = 0; i < 4; ++i) {
    int kl = ty + i * 8;
    tile[kl][tx] = __float2bfloat16(W[(size_t)(k0 + kl) * N + n0 + tx]);
  }
  __syncthreads();
#pragma unroll
  for (int i = 0; i < 4; ++i) {
    int nl = ty + i * 8;
    WT[(size_t)(n0 + nl) * K + k0 + tx] = tile[tx][nl];
  }
}

// ---------------- V global transpose: QKV V-region -> Vt[b][g][d][s] ----------------
__global__ void transpose_v(const bf16* __restrict__ Vsrc, bf16* __restrict__ Vt) {
  __shared__ bf16 tile[32][33];
  int bg = blockIdx.z;
  int b = bg >> 3, g = bg & 7;
  int s0 = blockIdx.x * 32, d0 = blockIdx.y * 32;
  int tx = threadIdx.x, ty = threadIdx.y;  // (32, 8)
#pragma unroll
  for (int i = 0; i < 4; ++i) {
    int sl = ty + i * 8;
    tile[sl][tx] = Vsrc[(size_t)(b * SEQ + s0 + sl) * QKVD + g * HD + d0 + tx];
  }
  __syncthreads();
#pragma unroll
  for (int i = 0; i < 4; ++i) {
    int dl = ty + i * 8;
    Vt[((size_t)(b * NKV + g) * HD + d0 + dl) * SEQ + s0 + tx] = tile[tx][dl];
  }
}

// ---------------- GEMM (8-phase, 256-row tile) ----------------
// 512 threads = 8 waves (2M x 4N), wave-out 128 x 16*NF, acc[8][NF].
// NF=4: B staging fully uniform (2+2 chunks/thread, vmcnt(4)) — fastest phases.
// NF=2: B-unit 1 uniform, vmcnt(3). (NF=3 retired: non-uniform staging cost ~20%.)
// Swizzle: 16B chunk c of row r at c^((r>>1)&3); pre-swizzled global source + linear
// gload_lds dest (0 conflicts). ROPE_LIM > 0: fused RoPE on cols n < ROPE_LIM.
// QSCALE: multiply output by SCALE_LOG2. Output at C[m*ldc + coloff + n].
template <int NF, bool OUT_BF16, int ROPE_LIM, bool QSCALE>
__global__ __launch_bounds__(512, 1) void gemm_bt4(const bf16* __restrict__ A,
                                                   const bf16* __restrict__ BT,
                                                   void* __restrict__ Cv,
                                                   const float* __restrict__ fcos,
                                                   const float* __restrict__ fsin,
                                                   int M, int N, int K, int gx,
                                                   int ldc, int coloff) {
  constexpr int BN = 64 * NF;
  constexpr int ASZ = 256 * 32;
  constexpr int BSZ = BN * 32;
  constexpr int SLOT = ASZ + BSZ;
  constexpr int HI = (NF + 1) / 2;
  extern __shared__ __align__(16) bf16 ls[];
  int nwg = gridDim.x;
  int flat = blockIdx.x;
  int swz = (flat & 7) * (nwg >> 3) + (flat >> 3);  // bijective: nwg % 8 == 0
  int bx = swz % gx, by = swz / gx;
  int m0 = by * 256, n0 = bx * BN;
  int tid = threadIdx.x, w = tid >> 6, lane = tid & 63;
  int wm = w >> 2, wn = w & 3;
  int lr = lane & 15, lk = lane >> 4;

  int aoff[2], adst[2];
#pragma unroll
  for (int i = 0; i < 2; ++i) {
    int t = i * 512 + tid;
    int row = t >> 2, c = t & 3;
    aoff[i] = row * K + ((c ^ ((row >> 1) & 3)) * 8);
    adst[i] = t * 8;
  }
  const int nb = (tid < 256) ? HI : NF / 2;
  const int bbase = (tid < 256) ? tid : HI * 256 + (tid - 256);
  int boff[HI], bdst[HI];
#pragma unroll
  for (int i = 0; i < HI; ++i) {
    int t = bbase + i * 256;
    if (t >= 256 * NF) t = 0;
    int row = t >> 2, c = t & 3;
    boff[i] = row * K + ((c ^ ((row >> 1) & 3)) * 8);
    bdst[i] = ASZ + t * 8;
  }
  const bf16* Ab = A + (size_t)m0 * K;
  const bf16* Bb = BT + (size_t)n0 * K;

  auto STAGE_A = [&](int kt, int h, int slot) {
    const bf16* s = Ab + kt * 64 + h * 32;
    bf16* d = ls + slot * SLOT;
#pragma unroll
    for (int i = 0; i < 2; ++i) gload16(s + aoff[i], d + adst[i]);
  };
  auto STAGE_B = [&](int kt, int h, int slot) {
    const bf16* s = Bb + kt * 64 + h * 32;
    bf16* d = ls + slot * SLOT;
#pragma unroll
    for (int i = 0; i < HI; ++i)
      if (i < nb) gload16(s + boff[i], d + bdst[i]);
  };
  auto WAITN = [&] {
    if constexpr (NF == 2) {
      asm volatile("s_waitcnt vmcnt(3)" ::: "memory");   // A 2 + B 1, uniform
    } else if constexpr (NF == 4) {
      asm volatile("s_waitcnt vmcnt(4)" ::: "memory");   // A 2 + B 2, uniform
    } else {
      if (tid < 256) asm volatile("s_waitcnt vmcnt(4)" ::: "memory");
      else           asm volatile("s_waitcnt vmcnt(3)" ::: "memory");
    }
  };

  f32x4 acc[8][NF] = {};
  bf16x8 aF[4], bF[NF];

  auto LDA = [&](int slot, int mh) {
    const bf16* base = ls + slot * SLOT;
#pragma unroll
    for (int mt = 0; mt < 4; ++mt) {
      int row = wm * 128 + (mh * 4 + mt) * 16 + lr;
      aF[mt] = *reinterpret_cast<const bf16x8*>(&base[row * 32 + ((lk ^ ((row >> 1) & 3)) * 8)]);
    }
  };
  auto LDB = [&](int slot) {
    const bf16* base = ls + slot * SLOT + ASZ;
#pragma unroll
    for (int nt = 0; nt < NF; ++nt) {
      int row = wn * (16 * NF) + nt * 16 + lr;
      bF[nt] = *reinterpret_cast<const bf16x8*>(&base[row * 32 + ((lk ^ ((row >> 1) & 3)) * 8)]);
    }
  };

#define PHASE(CSLOT, MH, STAGE_EXPR, DO_WAIT)                                       \
  {                                                                                 \
    __builtin_amdgcn_sched_barrier(0);                                              \
    if (MH == 0) LDB(CSLOT);                                                        \
    LDA(CSLOT, MH);                                                                 \
    STAGE_EXPR;                                                                     \
    __builtin_amdgcn_s_barrier();                                                   \
    asm volatile("s_waitcnt lgkmcnt(0)" ::: "memory");                              \
    __builtin_amdgcn_sched_barrier(0);                                              \
    __builtin_amdgcn_s_setprio(1);                                                  \
    _Pragma("unroll") for (int mt = 0; mt < 4; ++mt)                                \
        _Pragma("unroll") for (int nt = 0; nt < NF; ++nt)                           \
            acc[MH * 4 + mt][nt] =                                                  \
        __builtin_amdgcn_mfma_f32_16x16x32_bf16(aF[mt], bF[nt], acc[MH * 4 + mt][nt], 0, 0, 0); \
    __builtin_amdgcn_s_setprio(0);                                                  \
    if (DO_WAIT) WAITN();                                                           \
    __builtin_amdgcn_sched_barrier(0);                                              \
    __builtin_amdgcn_s_barrier();                                                   \
  }

  const int KT = K >> 6;
  const int IT = KT >> 1;

  STAGE_A(0, 0, 0); STAGE_B(0, 0, 0);
  STAGE_A(0, 1, 1); STAGE_B(0, 1, 1);
  STAGE_A(1, 0, 2); STAGE_B(1, 0, 2);
  WAITN();
  __builtin_amdgcn_s_barrier();

  for (int j = 0; j < IT; ++j) {
    int k1 = 2 * j + 1;
    int k2 = 2 * j + 2 < KT ? 2 * j + 2 : KT - 1;
    int k3 = 2 * j + 3 < KT ? 2 * j + 3 : KT - 1;
    PHASE(0, 0, STAGE_A(k1, 1, 3), false)
    PHASE(0, 1, STAGE_B(k1, 1, 3), false)
    PHASE(1, 0, STAGE_A(k2, 0, 0), false)
    PHASE(1, 1, STAGE_B(k2, 0, 0), true)
    PHASE(2, 0, STAGE_A(k2, 1, 1), false)
    PHASE(2, 1, STAGE_B(k2, 1, 1), false)
    PHASE(3, 0, STAGE_A(k3, 0, 2), false)
    PHASE(3, 1, STAGE_B(k3, 0, 2), true)
  }
  asm volatile("s_waitcnt vmcnt(0)" ::: "memory");
#undef PHASE

  // epilogue (optional fused RoPE + Q-scale)
#pragma unroll
  for (int fr = 0; fr < 8; ++fr)
#pragma unroll
    for (int nt = 0; nt < NF; ++nt)
#pragma unroll
      for (int r = 0; r < 4; ++r) {
        int m = m0 + wm * 128 + fr * 16 + lk * 4 + r;
        int n = n0 + wn * (16 * NF) + nt * 16 + lr;
        float v = acc[fr][nt][r];
        if (ROPE_LIM > 0) {
          float part = __shfl_xor(v, 1, 64);  // partner of the (2d,2d+1) pair
          if (n < ROPE_LIM) {
            int s = m & (SEQ - 1);
            int d2 = (n & (HD - 1)) >> 1;
            float c = fcos[s * 64 + d2];
            float sn = fsin[s * 64 + d2];
            v = (n & 1) ? (part * sn + v * c) : (v * c - part * sn);
          }
        }
        if (QSCALE) v *= SCALE_LOG2;
        if (OUT_BF16)
          reinterpret_cast<bf16*>(Cv)[(size_t)m * ldc + coloff + n] = __float2bfloat16(v);
        else
          reinterpret_cast<float*>(Cv)[(size_t)m * ldc + coloff + n] = v;
      }
}

// ---------------- Flash attention (swapped QK^T, 1-D grid, GLOBAL longest-first) ------
// Q pre-scaled by SCALE_LOG2 at projection (scores are log2-domain directly).
// Row-sum l via 2 extra MFMAs against a ones-B fragment (same row mapping as Oacc).
__global__ __launch_bounds__(256, 4) void attn_kernel(const bf16* __restrict__ QKV,
                                                      const bf16* __restrict__ Vt,
                                                      bf16* __restrict__ O) {
  __shared__ bf16 Klds[64 * 128];      // 16 KB
  __shared__ bf16 Vlds[128 * 64];      // 16 KB
  __shared__ bf16 Plds[4][16 * 64];    // 8 KB
  int bid = blockIdx.x;
  int qt = (SEQ / 64) - 1 - bid / (2 * NH);   // global longest-first
  int bh = bid % (2 * NH);
  int b = bh / NH, h = bh % NH, g = h / NREP;
  int tid = threadIdx.x, w = tid >> 6, lane = tid & 63;
  int lr = lane & 15, lk = lane >> 4;

  const bf16* kvK = QKV + ((size_t)b * SEQ) * QKVD + KOFF + g * HD;
  const bf16* kvVt = Vt + ((size_t)(b * NKV + g) * HD) * SEQ;
  int koff[4];
  bf16* kdst[4];
#pragma unroll
  for (int i = 0; i < 4; ++i) {
    int t = i * 256 + tid;
    int row = t >> 4, c = t & 15;
    int sc = c ^ (row & 7);
    koff[i] = row * QKVD + sc * 8;
    kdst[i] = Klds + t * 8;
  }
  int voff[4];
  bf16* vdst[4];
#pragma unroll
  for (int i = 0; i < 4; ++i) {
    int t = i * 256 + tid;
    int d = t >> 3, c = t & 7;
    int sc = c ^ (d & 7);
    voff[i] = d * SEQ + sc * 8;
    vdst[i] = Vlds + t * 8;
  }

  bf16* pb = Plds[w];

  short8 ones_s = {0x3F80, 0x3F80, 0x3F80, 0x3F80, 0x3F80, 0x3F80, 0x3F80, 0x3F80};
  bf16x8 ones = __builtin_bit_cast(bf16x8, ones_s);

  int q0 = qt * 64 + w * 16;
  int qrow = q0 + lr;

  bf16x8 aQ[4];
  {
    const bf16* qrp = QKV + ((size_t)(b * SEQ) + q0 + lr) * QKVD + h * HD;
#pragma unroll
    for (int kk = 0; kk < 4; ++kk)
      aQ[kk] = *reinterpret_cast<const bf16x8*>(qrp + kk * 32 + lk * 8);
  }

  f32x4 Oacc[8] = {};
  f32x4 lacc = {0.f, 0.f, 0.f, 0.f};
  float m_s = -1e30f;

  int jlast = qt * 64;
  for (int j0 = 0; j0 <= jlast; j0 += 64) {
    __syncthreads();
    {
      const bf16* ks = kvK + (size_t)j0 * QKVD;
      const bf16* vs = kvVt + j0;
#pragma unroll
      for (int i = 0; i < 4; ++i) gload16(ks + koff[i], kdst[i]);
#pragma unroll
      for (int i = 0; i < 4; ++i) gload16(vs + voff[i], vdst[i]);
    }
    __syncthreads();
    if (j0 > q0 + 15) continue;

    // ---- QK^T (swapped): sc4[nt][r] = S_log2[q=lr][k = nt*16 + lk*4 + r] ----
    f32x4 sc4[4] = {};
    __builtin_amdgcn_s_setprio(1);
#pragma unroll
    for (int kk = 0; kk < 4; ++kk) {
#pragma unroll
      for (int nt = 0; nt < 4; ++nt) {
        int jrow = nt * 16 + lr;
        int pos = (4 * kk + lk) ^ (lr & 7);
        bf16x8 bK = *reinterpret_cast<const bf16x8*>(&Klds[jrow * 128 + pos * 8]);
        sc4[nt] = __builtin_amdgcn_mfma_f32_16x16x32_bf16(bK, aQ[kk], sc4[nt], 0, 0, 0);
      }
    }
    __builtin_amdgcn_s_setprio(0);

    // ---- mask (diagonal tiles only) + lane-local max ----
    float sv[4][4], mxl = -3e38f;
    if (j0 + 63 > q0) {
#pragma unroll
      for (int nt = 0; nt < 4; ++nt)
#pragma unroll
        for (int r = 0; r < 4; ++r) {
          int col = j0 + nt * 16 + lk * 4 + r;
          sv[nt][r] = (col > qrow) ? -3e38f : sc4[nt][r];
          mxl = fmaxf(mxl, sv[nt][r]);
        }
    } else {
#pragma unroll
      for (int nt = 0; nt < 4; ++nt)
#pragma unroll
        for (int r = 0; r < 4; ++r) {
          sv[nt][r] = sc4[nt][r];
          mxl = fmaxf(mxl, sv[nt][r]);
        }
    }
    mxl = fmaxf(mxl, __shfl_xor(mxl, 16, 64));
    mxl = fmaxf(mxl, __shfl_xor(mxl, 32, 64));

    // exact defer-max
    if (__any(mxl > m_s)) {
      float mn = fmaxf(m_s, mxl);
      float alpha = exp2f(m_s - mn);
      m_s = mn;
      float ar[4];
#pragma unroll
      for (int r = 0; r < 4; ++r) ar[r] = __shfl(alpha, lk * 4 + r, 16);
#pragma unroll
      for (int nc = 0; nc < 8; ++nc)
#pragma unroll
        for (int r = 0; r < 4; ++r) Oacc[nc][r] *= ar[r];
#pragma unroll
      for (int r = 0; r < 4; ++r) lacc[r] *= ar[r];
    }
    float p[4][4];
#pragma unroll
    for (int nt = 0; nt < 4; ++nt)
#pragma unroll
      for (int r = 0; r < 4; ++r)
        p[nt][r] = exp2f(sv[nt][r] - m_s);

    // ---- P -> wave-private swizzled LDS, b64-packed ----
#pragma unroll
    for (int nt = 0; nt < 4; ++nt) {
      short4v pk;
      pk.x = bfbits(p[nt][0]);
      pk.y = bfbits(p[nt][1]);
      pk.z = bfbits(p[nt][2]);
      pk.w = bfbits(p[nt][3]);
      int chunk = (2 * nt + (lk >> 1)) ^ (lr & 7);
      *reinterpret_cast<short4v*>(&pb[lr * 64 + chunk * 8 + (lk & 1) * 4]) = pk;
    }
    asm volatile("s_waitcnt lgkmcnt(0)" ::: "memory");
    __builtin_amdgcn_sched_barrier(0);

    // ---- O += P @ V ; l += P @ 1 ----
    __builtin_amdgcn_s_setprio(1);
#pragma unroll
    for (int kb = 0; kb < 2; ++kb) {
      int px = ((kb * 4 + lk) ^ (lr & 7)) * 8;
      bf16x8 aP = *reinterpret_cast<const bf16x8*>(&pb[lr * 64 + px]);
#pragma unroll
      for (int nc = 0; nc < 8; ++nc) {
        bf16x8 bV = *reinterpret_cast<const bf16x8*>(&Vlds[(nc * 16 + lr) * 64 + px]);
        Oacc[nc] = __builtin_amdgcn_mfma_f32_16x16x32_bf16(aP, bV, Oacc[nc], 0, 0, 0);
      }
      lacc = __builtin_amdgcn_mfma_f32_16x16x32_bf16(aP, ones, lacc, 0, 0, 0);
    }
    __builtin_amdgcn_s_setprio(0);
  }

  // ---- epilogue ----
#pragma unroll
  for (int r = 0; r < 4; ++r) {
    float inv = 1.0f / lacc[r];
    size_t rowoff = ((size_t)(b * SEQ) + q0 + lk * 4 + r) * (NH * HD) + h * HD;
#pragma unroll
    for (int nc = 0; nc < 8; ++nc)
      O[rowoff + nc * 16 + lr] = __float2bfloat16(Oacc[nc][r] * inv);
  }
}

extern "C" void kernel_launch(void* const* d_in, const int* in_sizes, int n_in,
                              void* d_out, int out_size, void* d_ws, size_t ws_size,
                              hipStream_t stream) {
  const float* x = (const float*)d_in[0];
  const float* wq = (const float*)d_in[1];
  const float* wk = (const float*)d_in[2];
  const float* wv = (const float*)d_in[3];
  const float* wo = (const float*)d_in[4];
  const float* fc = (const float*)d_in[5];
  const float* fs = (const float*)d_in[6];
  float* out = (float*)d_out;
  (void)in_sizes; (void)n_in; (void)out_size; (void)ws_size;

  const int R = 2 * SEQ;        // 4096 rows
  const int DIMc = 3072;
  const int NQ = NH * HD;       // 3072

  char* ws = (char*)d_ws;
  bf16* xb = (bf16*)ws;     ws += (size_t)R * DIMc * 2;
  bf16* wqkvT = (bf16*)ws;  ws += (size_t)QKVD * DIMc * 2;
  bf16* woT = (bf16*)ws;    ws += (size_t)DIMc * NQ * 2;
  bf16* QKVb = (bf16*)ws;   ws += (size_t)R * QKVD * 2;
  bf16* Ob = (bf16*)ws;     ws += (size_t)R * NQ * 2;
  bf16* VtG = xb;  // aliases xb: dead after KV GEMM

  const int LDSB4 = 4 * (256 * 32 + 256 * 32) * 2;  // 131072 B (NF=4)
  const int LDSB2 = 4 * (256 * 32 + 128 * 32) * 2;  //  98304 B (NF=2)
  hipFuncSetAttribute((const void*)gemm_bt4<4, true, 3072, true>,
                      hipFuncAttributeMaxDynamicSharedMemorySize, LDSB4);
  hipFuncSetAttribute((const void*)gemm_bt4<2, true, 1024, false>,
                      hipFuncAttributeMaxDynamicSharedMemorySize, LDSB2);
  hipFuncSetAttribute((const void*)gemm_bt4<4, false, 0, false>,
                      hipFuncAttributeMaxDynamicSharedMemorySize, LDSB4);

  // 1) cast x to bf16
  {
    int n4 = R * DIMc / 4;
    cast_f32_bf16<<<n4 / 256, 256, 0, stream>>>(x, xb, n4);
  }
  // 2) transpose+cast all weights in one launch (z selects wq/wk/wv/wo)
  transpose_cast_all<<<dim3(96, 96, 4), dim3(32, 8), 0, stream>>>(
      wq, wk, wv, wo, wqkvT, woT);
  // 3a) Q projection + RoPE + scale fold: 256x256 tile, grid 12x16 = 192 blocks
  gemm_bt4<4, true, 3072, true><<<(NQ / 256) * (R / 256), 512, LDSB4, stream>>>(
      xb, wqkvT, QKVb, fc, fs, R, NQ, DIMc, NQ / 256, QKVD, 0);
  // 3b) K+V projection + RoPE(K only): 256x128 tile, grid 16x16 = 256 blocks
  gemm_bt4<2, true, 1024, false><<<(2048 / 128) * (R / 256), 512, LDSB2, stream>>>(
      xb, wqkvT + (size_t)KOFF * DIMc, QKVb, fc, fs, R, 2048, DIMc, 2048 / 128, QKVD, KOFF);
  // 4) V -> Vt[b][g][d][s]
  transpose_v<<<dim3(SEQ / 32, HD / 32, 2 * NKV), dim3(32, 8), 0, stream>>>(QKVb + VOFF, VtG);
  // 5) attention (1-D grid, global longest-first: 1536 blocks)
  attn_kernel<<<(SEQ / 64) * 2 * NH, 256, 0, stream>>>(QKVb, VtG, Ob);
  // 6) output projection: 256x256 tile, grid 12x16 = 192 blocks
  gemm_bt4<4, false, 0, false><<<(DIMc / 256) * (R / 256), 512, LDSB4, stream>>>(
      Ob, woT, out, nullptr, nullptr, R, DIMc, NQ, DIMc / 256, DIMc, 0);
}

// Round 20
// 369.841 us; speedup vs baseline: 1.0571x; 1.0571x over previous
//
#include <hip/hip_runtime.h>
#include <hip/hip_bf16.h>

typedef __hip_bfloat16 bf16;
typedef __bf16 bf16x8 __attribute__((ext_vector_type(8)));
typedef float f32x4 __attribute__((ext_vector_type(4)));
typedef short short8 __attribute__((ext_vector_type(8)));
typedef short short4v __attribute__((ext_vector_type(4)));

#define NH 24
#define NKV 8
#define HD 128
#define SEQ 2048
#define NREP 3
#define QKVD 5120              // fused QKV row stride (3072 + 1024 + 1024)
#define KOFF 3072              // K region offset in fused row
#define VOFF 4096              // V region offset in fused row
#define SCALE_LOG2 0.12751745f  // (1/sqrt(128)) * log2(e) — folded into Q at projection

__device__ inline void gload16(const void* g, void* l) {
  __builtin_amdgcn_global_load_lds(
      (const __attribute__((address_space(1))) void*)g,
      (__attribute__((address_space(3))) void*)l, 16, 0, 0);
}

__device__ inline short bfbits(float v) {
  return __builtin_bit_cast(short, __float2bfloat16(v));
}

// ---------------- cast f32 -> bf16 (vectorized) ----------------
__global__ void cast_f32_bf16(const float* __restrict__ in, bf16* __restrict__ out, int n4) {
  int i = blockIdx.x * 256 + threadIdx.x;
  if (i >= n4) return;
  float4 v = reinterpret_cast<const float4*>(in)[i];
  ushort4 u;
  u.x = __builtin_bit_cast(unsigned short, __float2bfloat16(v.x));
  u.y = __builtin_bit_cast(unsigned short, __float2bfloat16(v.y));
  u.z = __builtin_bit_cast(unsigned short, __float2bfloat16(v.z));
  u.w = __builtin_bit_cast(unsigned short, __float2bfloat16(v.w));
  reinterpret_cast<ushort4*>(out)[i] = u;
}

// ---------------- merged transpose + cast of all 4 weights (K = 3072 for all) --------
__global__ void transpose_cast_all(const float* __restrict__ wq, const float* __restrict__ wk,
                                   const float* __restrict__ wv, const float* __restrict__ wo,
                                   bf16* __restrict__ wqkvT, bf16* __restrict__ woT) {
  __shared__ bf16 tile[32][33];
  const int K = 3072;
  int z = blockIdx.z;
  const float* W;
  bf16* WT;
  int N;
  if (z == 0)      { W = wq; WT = wqkvT;                       N = 3072; }
  else if (z == 1) { W = wk; WT = wqkvT + (size_t)KOFF * K;    N = 1024; }
  else if (z == 2) { W = wv; WT = wqkvT + (size_t)VOFF * K;    N = 1024; }
  else             { W = wo; WT = woT;                         N = 3072; }
  int n0 = blockIdx.x * 32, k0 = blockIdx.y * 32;
  if (n0 >= N) return;
  int tx = threadIdx.x, ty = threadIdx.y;  // (32, 8)
#pragma unroll
  for (int i = 0; i < 4; ++i) {
    int kl = ty + i * 8;
    tile[kl][tx] = __float2bfloat16(W[(size_t)(k0 + kl) * N + n0 + tx]);
  }
  __syncthreads();
#pragma unroll
  for (int i = 0; i < 4; ++i) {
    int nl = ty + i * 8;
    WT[(size_t)(n0 + nl) * K + k0 + tx] = tile[tx][nl];
  }
}

// ---------------- V global transpose: QKV V-region -> Vt[b][g][d][s] ----------------
__global__ void transpose_v(const bf16* __restrict__ Vsrc, bf16* __restrict__ Vt) {
  __shared__ bf16 tile[32][33];
  int bg = blockIdx.z;
  int b = bg >> 3, g = bg & 7;
  int s0 = blockIdx.x * 32, d0 = blockIdx.y * 32;
  int tx = threadIdx.x, ty = threadIdx.y;  // (32, 8)
#pragma unroll
  for (int i = 0; i < 4; ++i) {
    int sl = ty + i * 8;
    tile[sl][tx] = Vsrc[(size_t)(b * SEQ + s0 + sl) * QKVD + g * HD + d0 + tx];
  }
  __syncthreads();
#pragma unroll
  for (int i = 0; i < 4; ++i) {
    int dl = ty + i * 8;
    Vt[((size_t)(b * NKV + g) * HD + d0 + dl) * SEQ + s0 + tx] = tile[tx][dl];
  }
}

// ---------------- GEMM (8-phase, 256-row tile, exact-pack grids) ----------------
// 512 threads = 8 waves (2M x 4N), wave-out 128 x 16*NF, acc[8][NF] (NF<=3: <=96 VGPR).
// LDS: 4 half-slots x (A 256x32 + B 64*NF x 32). Swizzle: 16B chunk c of row r at
// c^((r>>1)&3); pre-swizzled global source + linear gload_lds dest (0 conflicts).
// ROPE_LIM > 0: fused RoPE on cols n < ROPE_LIM. QSCALE: multiply output by SCALE_LOG2.
// Output at C[m*ldc + coloff + n]. NF=3 (Q/WO): 256 blocks exact; NF=2 (KV): 256 exact.
template <int NF, bool OUT_BF16, int ROPE_LIM, bool QSCALE>
__global__ __launch_bounds__(512, 1) void gemm_bt4(const bf16* __restrict__ A,
                                                   const bf16* __restrict__ BT,
                                                   void* __restrict__ Cv,
                                                   const float* __restrict__ fcos,
                                                   const float* __restrict__ fsin,
                                                   int M, int N, int K, int gx,
                                                   int ldc, int coloff) {
  constexpr int BN = 64 * NF;
  constexpr int ASZ = 256 * 32;
  constexpr int BSZ = BN * 32;
  constexpr int SLOT = ASZ + BSZ;
  constexpr int HI = (NF + 1) / 2;
  extern __shared__ __align__(16) bf16 ls[];
  int nwg = gridDim.x;
  int flat = blockIdx.x;
  int swz = (flat & 7) * (nwg >> 3) + (flat >> 3);  // bijective: nwg % 8 == 0
  int bx = swz % gx, by = swz / gx;
  int m0 = by * 256, n0 = bx * BN;
  int tid = threadIdx.x, w = tid >> 6, lane = tid & 63;
  int wm = w >> 2, wn = w & 3;
  int lr = lane & 15, lk = lane >> 4;

  int aoff[2], adst[2];
#pragma unroll
  for (int i = 0; i < 2; ++i) {
    int t = i * 512 + tid;
    int row = t >> 2, c = t & 3;
    aoff[i] = row * K + ((c ^ ((row >> 1) & 3)) * 8);
    adst[i] = t * 8;
  }
  const int nb = (tid < 256) ? HI : NF / 2;
  const int bbase = (tid < 256) ? tid : HI * 256 + (tid - 256);
  int boff[HI], bdst[HI];
#pragma unroll
  for (int i = 0; i < HI; ++i) {
    int t = bbase + i * 256;
    if (t >= 256 * NF) t = 0;
    int row = t >> 2, c = t & 3;
    boff[i] = row * K + ((c ^ ((row >> 1) & 3)) * 8);
    bdst[i] = ASZ + t * 8;
  }
  const bf16* Ab = A + (size_t)m0 * K;
  const bf16* Bb = BT + (size_t)n0 * K;

  auto STAGE_A = [&](int kt, int h, int slot) {
    const bf16* s = Ab + kt * 64 + h * 32;
    bf16* d = ls + slot * SLOT;
#pragma unroll
    for (int i = 0; i < 2; ++i) gload16(s + aoff[i], d + adst[i]);
  };
  auto STAGE_B = [&](int kt, int h, int slot) {
    const bf16* s = Bb + kt * 64 + h * 32;
    bf16* d = ls + slot * SLOT;
#pragma unroll
    for (int i = 0; i < HI; ++i)
      if (i < nb) gload16(s + boff[i], d + bdst[i]);
  };
  auto WAITN = [&] {
    if constexpr (NF == 2) {
      asm volatile("s_waitcnt vmcnt(3)" ::: "memory");   // A 2 + B 1, uniform
    } else {
      if (tid < 256) asm volatile("s_waitcnt vmcnt(4)" ::: "memory");
      else           asm volatile("s_waitcnt vmcnt(3)" ::: "memory");
    }
  };

  f32x4 acc[8][NF] = {};
  bf16x8 aF[4], bF[NF];

  auto LDA = [&](int slot, int mh) {
    const bf16* base = ls + slot * SLOT;
#pragma unroll
    for (int mt = 0; mt < 4; ++mt) {
      int row = wm * 128 + (mh * 4 + mt) * 16 + lr;
      aF[mt] = *reinterpret_cast<const bf16x8*>(&base[row * 32 + ((lk ^ ((row >> 1) & 3)) * 8)]);
    }
  };
  auto LDB = [&](int slot) {
    const bf16* base = ls + slot * SLOT + ASZ;
#pragma unroll
    for (int nt = 0; nt < NF; ++nt) {
      int row = wn * (16 * NF) + nt * 16 + lr;
      bF[nt] = *reinterpret_cast<const bf16x8*>(&base[row * 32 + ((lk ^ ((row >> 1) & 3)) * 8)]);
    }
  };

#define PHASE(CSLOT, MH, STAGE_EXPR, DO_WAIT)                                       \
  {                                                                                 \
    __builtin_amdgcn_sched_barrier(0);                                              \
    if (MH == 0) LDB(CSLOT);                                                        \
    LDA(CSLOT, MH);                                                                 \
    STAGE_EXPR;                                                                     \
    __builtin_amdgcn_s_barrier();                                                   \
    asm volatile("s_waitcnt lgkmcnt(0)" ::: "memory");                              \
    __builtin_amdgcn_sched_barrier(0);                                              \
    __builtin_amdgcn_s_setprio(1);                                                  \
    _Pragma("unroll") for (int mt = 0; mt < 4; ++mt)                                \
        _Pragma("unroll") for (int nt = 0; nt < NF; ++nt)                           \
            acc[MH * 4 + mt][nt] =                                                  \
        __builtin_amdgcn_mfma_f32_16x16x32_bf16(aF[mt], bF[nt], acc[MH * 4 + mt][nt], 0, 0, 0); \
    __builtin_amdgcn_s_setprio(0);                                                  \
    if (DO_WAIT) WAITN();                                                           \
    __builtin_amdgcn_sched_barrier(0);                                              \
    __builtin_amdgcn_s_barrier();                                                   \
  }

  const int KT = K >> 6;
  const int IT = KT >> 1;

  STAGE_A(0, 0, 0); STAGE_B(0, 0, 0);
  STAGE_A(0, 1, 1); STAGE_B(0, 1, 1);
  STAGE_A(1, 0, 2); STAGE_B(1, 0, 2);
  WAITN();
  __builtin_amdgcn_s_barrier();

  for (int j = 0; j < IT; ++j) {
    int k1 = 2 * j + 1;
    int k2 = 2 * j + 2 < KT ? 2 * j + 2 : KT - 1;
    int k3 = 2 * j + 3 < KT ? 2 * j + 3 : KT - 1;
    PHASE(0, 0, STAGE_A(k1, 1, 3), false)
    PHASE(0, 1, STAGE_B(k1, 1, 3), false)
    PHASE(1, 0, STAGE_A(k2, 0, 0), false)
    PHASE(1, 1, STAGE_B(k2, 0, 0), true)
    PHASE(2, 0, STAGE_A(k2, 1, 1), false)
    PHASE(2, 1, STAGE_B(k2, 1, 1), false)
    PHASE(3, 0, STAGE_A(k3, 0, 2), false)
    PHASE(3, 1, STAGE_B(k3, 0, 2), true)
  }
  asm volatile("s_waitcnt vmcnt(0)" ::: "memory");
#undef PHASE

  // epilogue (optional fused RoPE + Q-scale)
#pragma unroll
  for (int fr = 0; fr < 8; ++fr)
#pragma unroll
    for (int nt = 0; nt < NF; ++nt)
#pragma unroll
      for (int r = 0; r < 4; ++r) {
        int m = m0 + wm * 128 + fr * 16 + lk * 4 + r;
        int n = n0 + wn * (16 * NF) + nt * 16 + lr;
        float v = acc[fr][nt][r];
        if (ROPE_LIM > 0) {
          float part = __shfl_xor(v, 1, 64);  // partner of the (2d,2d+1) pair
          if (n < ROPE_LIM) {
            int s = m & (SEQ - 1);
            int d2 = (n & (HD - 1)) >> 1;
            float c = fcos[s * 64 + d2];
            float sn = fsin[s * 64 + d2];
            v = (n & 1) ? (part * sn + v * c) : (v * c - part * sn);
          }
        }
        if (QSCALE) v *= SCALE_LOG2;
        if (OUT_BF16)
          reinterpret_cast<bf16*>(Cv)[(size_t)m * ldc + coloff + n] = __float2bfloat16(v);
        else
          reinterpret_cast<float*>(Cv)[(size_t)m * ldc + coloff + n] = v;
      }
}

// ---------------- Flash attention (swapped QK^T, 1-D grid, GLOBAL longest-first) ------
// Q pre-scaled by SCALE_LOG2 at projection (scores are log2-domain directly).
// Row-sum l via 2 extra MFMAs against a ones-B fragment (same row mapping as Oacc).
__global__ __launch_bounds__(256, 4) void attn_kernel(const bf16* __restrict__ QKV,
                                                      const bf16* __restrict__ Vt,
                                                      bf16* __restrict__ O) {
  __shared__ bf16 Klds[64 * 128];      // 16 KB
  __shared__ bf16 Vlds[128 * 64];      // 16 KB
  __shared__ bf16 Plds[4][16 * 64];    // 8 KB
  int bid = blockIdx.x;
  int qt = (SEQ / 64) - 1 - bid / (2 * NH);   // global longest-first
  int bh = bid % (2 * NH);
  int b = bh / NH, h = bh % NH, g = h / NREP;
  int tid = threadIdx.x, w = tid >> 6, lane = tid & 63;
  int lr = lane & 15, lk = lane >> 4;

  const bf16* kvK = QKV + ((size_t)b * SEQ) * QKVD + KOFF + g * HD;
  const bf16* kvVt = Vt + ((size_t)(b * NKV + g) * HD) * SEQ;
  int koff[4];
  bf16* kdst[4];
#pragma unroll
  for (int i = 0; i < 4; ++i) {
    int t = i * 256 + tid;
    int row = t >> 4, c = t & 15;
    int sc = c ^ (row & 7);
    koff[i] = row * QKVD + sc * 8;
    kdst[i] = Klds + t * 8;
  }
  int voff[4];
  bf16* vdst[4];
#pragma unroll
  for (int i = 0; i < 4; ++i) {
    int t = i * 256 + tid;
    int d = t >> 3, c = t & 7;
    int sc = c ^ (d & 7);
    voff[i] = d * SEQ + sc * 8;
    vdst[i] = Vlds + t * 8;
  }

  bf16* pb = Plds[w];

  short8 ones_s = {0x3F80, 0x3F80, 0x3F80, 0x3F80, 0x3F80, 0x3F80, 0x3F80, 0x3F80};
  bf16x8 ones = __builtin_bit_cast(bf16x8, ones_s);

  int q0 = qt * 64 + w * 16;
  int qrow = q0 + lr;

  bf16x8 aQ[4];
  {
    const bf16* qrp = QKV + ((size_t)(b * SEQ) + q0 + lr) * QKVD + h * HD;
#pragma unroll
    for (int kk = 0; kk < 4; ++kk)
      aQ[kk] = *reinterpret_cast<const bf16x8*>(qrp + kk * 32 + lk * 8);
  }

  f32x4 Oacc[8] = {};
  f32x4 lacc = {0.f, 0.f, 0.f, 0.f};
  float m_s = -1e30f;

  int jlast = qt * 64;
  for (int j0 = 0; j0 <= jlast; j0 += 64) {
    __syncthreads();
    {
      const bf16* ks = kvK + (size_t)j0 * QKVD;
      const bf16* vs = kvVt + j0;
#pragma unroll
      for (int i = 0; i < 4; ++i) gload16(ks + koff[i], kdst[i]);
#pragma unroll
      for (int i = 0; i < 4; ++i) gload16(vs + voff[i], vdst[i]);
    }
    __syncthreads();
    if (j0 > q0 + 15) continue;

    // ---- QK^T (swapped): sc4[nt][r] = S_log2[q=lr][k = nt*16 + lk*4 + r] ----
    f32x4 sc4[4] = {};
    __builtin_amdgcn_s_setprio(1);
#pragma unroll
    for (int kk = 0; kk < 4; ++kk) {
#pragma unroll
      for (int nt = 0; nt < 4; ++nt) {
        int jrow = nt * 16 + lr;
        int pos = (4 * kk + lk) ^ (lr & 7);
        bf16x8 bK = *reinterpret_cast<const bf16x8*>(&Klds[jrow * 128 + pos * 8]);
        sc4[nt] = __builtin_amdgcn_mfma_f32_16x16x32_bf16(bK, aQ[kk], sc4[nt], 0, 0, 0);
      }
    }
    __builtin_amdgcn_s_setprio(0);

    // ---- mask (diagonal tiles only) + lane-local max ----
    float sv[4][4], mxl = -3e38f;
    if (j0 + 63 > q0) {
#pragma unroll
      for (int nt = 0; nt < 4; ++nt)
#pragma unroll
        for (int r = 0; r < 4; ++r) {
          int col = j0 + nt * 16 + lk * 4 + r;
          sv[nt][r] = (col > qrow) ? -3e38f : sc4[nt][r];
          mxl = fmaxf(mxl, sv[nt][r]);
        }
    } else {
#pragma unroll
      for (int nt = 0; nt < 4; ++nt)
#pragma unroll
        for (int r = 0; r < 4; ++r) {
          sv[nt][r] = sc4[nt][r];
          mxl = fmaxf(mxl, sv[nt][r]);
        }
    }
    mxl = fmaxf(mxl, __shfl_xor(mxl, 16, 64));
    mxl = fmaxf(mxl, __shfl_xor(mxl, 32, 64));

    // exact defer-max
    if (__any(mxl > m_s)) {
      float mn = fmaxf(m_s, mxl);
      float alpha = exp2f(m_s - mn);
      m_s = mn;
      float ar[4];
#pragma unroll
      for (int r = 0; r < 4; ++r) ar[r] = __shfl(alpha, lk * 4 + r, 16);
#pragma unroll
      for (int nc = 0; nc < 8; ++nc)
#pragma unroll
        for (int r = 0; r < 4; ++r) Oacc[nc][r] *= ar[r];
#pragma unroll
      for (int r = 0; r < 4; ++r) lacc[r] *= ar[r];
    }
    float p[4][4];
#pragma unroll
    for (int nt = 0; nt < 4; ++nt)
#pragma unroll
      for (int r = 0; r < 4; ++r)
        p[nt][r] = exp2f(sv[nt][r] - m_s);

    // ---- P -> wave-private swizzled LDS, b64-packed ----
#pragma unroll
    for (int nt = 0; nt < 4; ++nt) {
      short4v pk;
      pk.x = bfbits(p[nt][0]);
      pk.y = bfbits(p[nt][1]);
      pk.z = bfbits(p[nt][2]);
      pk.w = bfbits(p[nt][3]);
      int chunk = (2 * nt + (lk >> 1)) ^ (lr & 7);
      *reinterpret_cast<short4v*>(&pb[lr * 64 + chunk * 8 + (lk & 1) * 4]) = pk;
    }
    asm volatile("s_waitcnt lgkmcnt(0)" ::: "memory");
    __builtin_amdgcn_sched_barrier(0);

    // ---- O += P @ V ; l += P @ 1 ----
    __builtin_amdgcn_s_setprio(1);
#pragma unroll
    for (int kb = 0; kb < 2; ++kb) {
      int px = ((kb * 4 + lk) ^ (lr & 7)) * 8;
      bf16x8 aP = *reinterpret_cast<const bf16x8*>(&pb[lr * 64 + px]);
#pragma unroll
      for (int nc = 0; nc < 8; ++nc) {
        bf16x8 bV = *reinterpret_cast<const bf16x8*>(&Vlds[(nc * 16 + lr) * 64 + px]);
        Oacc[nc] = __builtin_amdgcn_mfma_f32_16x16x32_bf16(aP, bV, Oacc[nc], 0, 0, 0);
      }
      lacc = __builtin_amdgcn_mfma_f32_16x16x32_bf16(aP, ones, lacc, 0, 0, 0);
    }
    __builtin_amdgcn_s_setprio(0);
  }

  // ---- epilogue ----
#pragma unroll
  for (int r = 0; r < 4; ++r) {
    float inv = 1.0f / lacc[r];
    size_t rowoff = ((size_t)(b * SEQ) + q0 + lk * 4 + r) * (NH * HD) + h * HD;
#pragma unroll
    for (int nc = 0; nc < 8; ++nc)
      O[rowoff + nc * 16 + lr] = __float2bfloat16(Oacc[nc][r] * inv);
  }
}

extern "C" void kernel_launch(void* const* d_in, const int* in_sizes, int n_in,
                              void* d_out, int out_size, void* d_ws, size_t ws_size,
                              hipStream_t stream) {
  const float* x = (const float*)d_in[0];
  const float* wq = (const float*)d_in[1];
  const float* wk = (const float*)d_in[2];
  const float* wv = (const float*)d_in[3];
  const float* wo = (const float*)d_in[4];
  const float* fc = (const float*)d_in[5];
  const float* fs = (const float*)d_in[6];
  float* out = (float*)d_out;
  (void)in_sizes; (void)n_in; (void)out_size; (void)ws_size;

  const int R = 2 * SEQ;        // 4096 rows
  const int DIMc = 3072;
  const int NQ = NH * HD;       // 3072

  char* ws = (char*)d_ws;
  bf16* xb = (bf16*)ws;     ws += (size_t)R * DIMc * 2;
  bf16* wqkvT = (bf16*)ws;  ws += (size_t)QKVD * DIMc * 2;
  bf16* woT = (bf16*)ws;    ws += (size_t)DIMc * NQ * 2;
  bf16* QKVb = (bf16*)ws;   ws += (size_t)R * QKVD * 2;
  bf16* Ob = (bf16*)ws;     ws += (size_t)R * NQ * 2;
  bf16* VtG = xb;  // aliases xb: dead after KV GEMM

  const int LDSB3 = 4 * (256 * 32 + 192 * 32) * 2;  // 114688 B (NF=3)
  const int LDSB2 = 4 * (256 * 32 + 128 * 32) * 2;  //  98304 B (NF=2)
  hipFuncSetAttribute((const void*)gemm_bt4<3, true, 3072, true>,
                      hipFuncAttributeMaxDynamicSharedMemorySize, LDSB3);
  hipFuncSetAttribute((const void*)gemm_bt4<2, true, 1024, false>,
                      hipFuncAttributeMaxDynamicSharedMemorySize, LDSB2);
  hipFuncSetAttribute((const void*)gemm_bt4<3, false, 0, false>,
                      hipFuncAttributeMaxDynamicSharedMemorySize, LDSB3);

  // 1) cast x to bf16
  {
    int n4 = R * DIMc / 4;
    cast_f32_bf16<<<n4 / 256, 256, 0, stream>>>(x, xb, n4);
  }
  // 2) transpose+cast all weights in one launch (z selects wq/wk/wv/wo)
  transpose_cast_all<<<dim3(96, 96, 4), dim3(32, 8), 0, stream>>>(
      wq, wk, wv, wo, wqkvT, woT);
  // 3a) Q projection + RoPE + scale fold: 256x192 tile, grid 16x16 = 256 blocks
  gemm_bt4<3, true, 3072, true><<<(NQ / 192) * (R / 256), 512, LDSB3, stream>>>(
      xb, wqkvT, QKVb, fc, fs, R, NQ, DIMc, NQ / 192, QKVD, 0);
  // 3b) K+V projection + RoPE(K only): 256x128 tile, grid 16x16 = 256 blocks
  gemm_bt4<2, true, 1024, false><<<(2048 / 128) * (R / 256), 512, LDSB2, stream>>>(
      xb, wqkvT + (size_t)KOFF * DIMc, QKVb, fc, fs, R, 2048, DIMc, 2048 / 128, QKVD, KOFF);
  // 4) V -> Vt[b][g][d][s]
  transpose_v<<<dim3(SEQ / 32, HD / 32, 2 * NKV), dim3(32, 8), 0, stream>>>(QKVb + VOFF, VtG);
  // 5) attention (1-D grid, global longest-first: 1536 blocks)
  attn_kernel<<<(SEQ / 64) * 2 * NH, 256, 0, stream>>>(QKVb, VtG, Ob);
  // 6) output projection: 256x192 tile, grid 16x16 = 256 blocks
  gemm_bt4<3, false, 0, false><<<(DIMc / 192) * (R / 256), 512, LDSB3, stream>>>(
      Ob, woT, out, nullptr, nullptr, R, DIMc, NQ, DIMc / 192, DIMc, 0);
}